// Round 1
// baseline (1203.610 us; speedup 1.0000x reference)
//
#include <hip/hip_runtime.h>
#include <cstdint>

#define H       192
#define TWOH    384
#define PATCHES 64
#define RADIUS  0.42f
#define BSCALE  0.18f
#define NEGINF  -1e9f

#define MT 128      // rows per block
#define KT 32       // K chunk
#define SA 132      // k-row stride (floats) for staged A/B tiles (== 4 mod 32)

// Bijective swizzled address for the 128x128 logits/weights overlay (64 KB exactly).
// col' = col ^ ((row>>3)&3) spreads the 8x8-per-thread parking writes (<=4-way);
// row rotation ((row+col')&127) gives conflict-free per-row reads in phase 3
// (bank == (row + col') % 32, distinct across the 32 rows a wave touches).
__device__ __forceinline__ int lsAddr(int col, int row) {
  int cp = col ^ ((row >> 3) & 3);
  return (cp << 7) + ((row + cp) & 127);
}

__global__ __launch_bounds__(256, 2)
void taps_fused_kernel(const float* __restrict__ tok, const float* __restrict__ prv,
                       const float* __restrict__ Wsel, const float* __restrict__ bsel,
                       const float* __restrict__ Wbr,  const float* __restrict__ bbr,
                       const float* __restrict__ pv,   const float* __restrict__ pp,
                       float* __restrict__ out, int B) {
  __shared__ float smem[16384];            // 65536 B: At[32][132] + Bs[32][132] overlaid by Ls
  float* At  = smem;
  float* Bst = smem + KT * SA;

  const int t = threadIdx.x;
  const int row0 = blockIdx.x * MT;
  const int tr = t >> 4, tc = t & 15;
  const int r0 = tr << 3, c0 = tc << 3;

  // staging decomposition: slot = t + 256*i -> (row/col = sr+32i, k4 = sk4)
  const int sr  = t >> 3;                  // 0..31
  const int sk4 = t & 7;                   // float4 index along K
  const int sx8 = (sk4 & 3) << 3;          // XOR swizzle for staged row index
  const int skb = sk4 << 2;                // k offset within chunk

  const size_t oW = (size_t)B * 192, oA = (size_t)B * 256, oLM = (size_t)B * 259,
               oBM = (size_t)B * 260, oMD = (size_t)B * 261, oR = (size_t)B * 262,
               oS = (size_t)B * 263;

  float acc[8][8];
#pragma unroll
  for (int i = 0; i < 8; i++)
#pragma unroll
    for (int j = 0; j < 8; j++) acc[i][j] = 0.f;

  // ---- Phase 1: logits[128][128] = [tok|prv][128][384] @ Wcat^T ----
  float4 aR[4], bR[4];
  // prefetch chunk 0 into registers
#pragma unroll
  for (int i = 0; i < 4; i++) {
    int gr = row0 + sr + (i << 5); if (gr >= B) gr = B - 1;
    aR[i] = *(const float4*)(tok + (size_t)gr * H + skb);
    int n = sr + (i << 5);
    const float* wr = (n < PATCHES) ? (Wsel + (size_t)n * TWOH)
                                    : (Wbr + (size_t)(n - PATCHES) * TWOH);
    bR[i] = *(const float4*)(wr + skb);
  }

  for (int kb = 0; kb < TWOH / KT; kb++) {
    __syncthreads();                        // previous compute done reading LDS
    {
      float* pA = At  + skb * SA;
      float* pB = Bst + skb * SA;
#pragma unroll
      for (int i = 0; i < 4; i++) {
        int rx = (sr + (i << 5)) ^ sx8;     // swizzled transposed store (<=2-way)
        pA[rx]          = aR[i].x;
        pA[SA + rx]     = aR[i].y;
        pA[2 * SA + rx] = aR[i].z;
        pA[3 * SA + rx] = aR[i].w;
        pB[rx]          = bR[i].x;
        pB[SA + rx]     = bR[i].y;
        pB[2 * SA + rx] = bR[i].z;
        pB[3 * SA + rx] = bR[i].w;
      }
    }
    __syncthreads();
    if (kb < TWOH / KT - 1) {               // T14: issue next chunk loads, hide under compute
      int kc = (kb + 1) * KT;
      const float* src = (kc < H) ? tok : prv;
      int koff = ((kc < H) ? kc : kc - H) + skb;
#pragma unroll
      for (int i = 0; i < 4; i++) {
        int gr = row0 + sr + (i << 5); if (gr >= B) gr = B - 1;
        aR[i] = *(const float4*)(src + (size_t)gr * H + koff);
        int n = sr + (i << 5);
        const float* wr = (n < PATCHES) ? (Wsel + (size_t)n * TWOH)
                                        : (Wbr + (size_t)(n - PATCHES) * TWOH);
        bR[i] = *(const float4*)(wr + kc + skb);
      }
    }
#pragma unroll
    for (int k = 0; k < KT; k++) {
      const int m = (k >> 2) & 3;           // matches staging XOR: k>>2 == k4
      const float* ap = At  + k * SA + ((tr ^ m) << 3);
      const float* bp = Bst + k * SA + ((tc ^ m) << 3);
      float4 a0 = *(const float4*)(ap);
      float4 a1 = *(const float4*)(ap + 4);
      float4 b0 = *(const float4*)(bp);
      float4 b1 = *(const float4*)(bp + 4);
      float av[8] = {a0.x, a0.y, a0.z, a0.w, a1.x, a1.y, a1.z, a1.w};
      float bv[8] = {b0.x, b0.y, b0.z, b0.w, b1.x, b1.y, b1.z, b1.w};
#pragma unroll
      for (int i = 0; i < 8; i++)
#pragma unroll
        for (int j = 0; j < 8; j++)
          acc[i][j] = fmaf(av[i], bv[j], acc[i][j]);
    }
  }

  // bias + park logits into swizzled overlay
  float bias[8];
#pragma unroll
  for (int j = 0; j < 8; j++) {
    int n = c0 + j;
    bias[j] = (n < PATCHES) ? bsel[n] : bbr[n - PATCHES];
  }
  __syncthreads();
#pragma unroll
  for (int i = 0; i < 8; i++)
#pragma unroll
    for (int j = 0; j < 8; j++)
      smem[lsAddr(c0 + j, r0 + i)] = acc[i][j] + bias[j];
  __syncthreads();

  // ---- Phase 3: per-row postprocess, 2 lanes per row (lane = row x half) ----
  {
    const int lane = t & 63;
    const int wv = t >> 6;
    const int rl = lane & 31;
    const int h  = lane >> 5;
    const int row = (wv << 5) + rl;
    const int rowg = row0 + row;
    const bool valid = rowg < B;
    const int kb0 = h << 5;                 // this lane's 32-patch slice

    // lattice coords straight from pp (exact reference values):
    // patch k = (c[k>>4], c[(k>>2)&3], c[k&3]); c[q] = pp[48q]
    const float lc0 = pp[0], lc1 = pp[48], lc2 = pp[96], lc3 = pp[144];
    const float pxA = h ? lc2 : lc0;        // x coord for i<16
    const float pxB = h ? lc3 : lc1;        // x coord for i>=16
#define CSEL(q) ((q) == 0 ? lc0 : (q) == 1 ? lc1 : (q) == 2 ? lc2 : lc3)

    float se[32], da[32], bl[32];

    // softmax over sel logits
    float mxv = -3.0e38f;
#pragma unroll
    for (int i = 0; i < 32; i++) {
      float v = smem[lsAddr(kb0 + i, row)];
      se[i] = v;
      mxv = fmaxf(mxv, v);
    }
    mxv = fmaxf(mxv, __shfl_xor(mxv, 32, 64));

    float s = 0.f, apx = 0.f, apy = 0.f, apz = 0.f;
#pragma unroll
    for (int i = 0; i < 32; i++) {
      float e = __expf(se[i] - mxv);
      se[i] = e;
      s += e;
      float px = (i < 16) ? pxA : pxB;
      float py = CSEL((i >> 2) & 3);
      float pz = CSEL(i & 3);
      apx = fmaf(e, px, apx);
      apy = fmaf(e, py, apy);
      apz = fmaf(e, pz, apz);
    }
    s   += __shfl_xor(s, 32, 64);
    apx += __shfl_xor(apx, 32, 64);
    apy += __shfl_xor(apy, 32, 64);
    apz += __shfl_xor(apz, 32, 64);
    const float inv_s = 1.0f / s;
    const float ax = apx * inv_s, ay = apy * inv_s, az = apz * inv_s;

    // distances + nearest (first-index tie-break; h=0 indices precede h=1)
    float dmin = 3.0e38f; int nidx = 0;
#pragma unroll
    for (int i = 0; i < 32; i++) {
      float px = (i < 16) ? pxA : pxB;
      float py = CSEL((i >> 2) & 3);
      float pz = CSEL(i & 3);
      float dx = ax - px, dy = ay - py, dz = az - pz;
      float d2 = fmaf(dx, dx, fmaf(dy, dy, dz * dz));
      float d = sqrtf(d2);
      da[i] = d;
      if (d < dmin) { dmin = d; nidx = kb0 + i; }
    }
    {
      float od = __shfl_xor(dmin, 32, 64);
      int   oi = __shfl_xor(nidx, 32, 64);
      if (od < dmin || (od == dmin && oi < nidx)) { dmin = od; nidx = oi; }
    }

    // bridge logits: mask locals, per-half sorted top-6 (insertion network,
    // strict compare keeps earlier index on ties, like lax.top_k)
    float q0 = -3.0e38f, q1 = -3.0e38f, q2 = -3.0e38f,
          q3 = -3.0e38f, q4 = -3.0e38f, q5 = -3.0e38f;
#pragma unroll
    for (int i = 0; i < 32; i++) {
      float v = smem[lsAddr(64 + kb0 + i, row)];
      bool loc = (da[i] <= RADIUS) || (kb0 + i == nidx);
      v = loc ? NEGINF : v;
      bl[i] = v;
      float c = v, n;
      n = fmaxf(q0, c); c = fminf(q0, c); q0 = n;
      n = fmaxf(q1, c); c = fminf(q1, c); q1 = n;
      n = fmaxf(q2, c); c = fminf(q2, c); q2 = n;
      n = fmaxf(q3, c); c = fminf(q3, c); q3 = n;
      n = fmaxf(q4, c); c = fminf(q4, c); q4 = n;
      q5 = fmaxf(q5, c);
    }
    // merge the two sorted-6 lists: r-th largest = max(t_r, o_r, max_i min(t_i, o_{r-1-i}))
    const float o0 = __shfl_xor(q0, 32, 64), o1 = __shfl_xor(q1, 32, 64),
                o2 = __shfl_xor(q2, 32, 64), o3 = __shfl_xor(q3, 32, 64),
                o4 = __shfl_xor(q4, 32, 64), o5 = __shfl_xor(q5, 32, 64);
    const float v0 = fmaxf(q0, o0);
    const float v1 = fmaxf(fmaxf(q1, o1), fminf(q0, o0));
    const float v2 = fmaxf(fmaxf(q2, o2), fmaxf(fminf(q0, o1), fminf(q1, o0)));
    const float v3 = fmaxf(fmaxf(q3, o3),
                     fmaxf(fmaxf(fminf(q0, o2), fminf(q1, o1)), fminf(q2, o0)));
    const float v4 = fmaxf(fmaxf(q4, o4),
                     fmaxf(fmaxf(fminf(q0, o3), fminf(q1, o2)),
                           fmaxf(fminf(q2, o1), fminf(q3, o0))));
    const float v5 = fmaxf(fmaxf(q5, o5),
                     fmaxf(fmaxf(fminf(q0, o4), fminf(q1, o3)),
                           fmaxf(fminf(q2, o2),
                                 fmaxf(fminf(q3, o1), fminf(q4, o0)))));
    const float m6 = v0;
    const float esum = 1.0f + __expf(v1 - m6) + __expf(v2 - m6) +
                       __expf(v3 - m6) + __expf(v4 - m6) + __expf(v5 - m6);
    const float inv_e = 1.0f / esum;
    const float thr = v5;

    // membership with exact lower-index-first tie handling
    int ng = 0, ne = 0;
#pragma unroll
    for (int i = 0; i < 32; i++) {
      ng += (bl[i] > thr) ? 1 : 0;
      ne += (bl[i] == thr) ? 1 : 0;
    }
    const int ngTot = ng + __shfl_xor(ng, 32, 64);
    const int neOth = __shfl_xor(ne, 32, 64);
    const int eqStart = h ? neOth : 0;      // h=1 equals rank after all h=0 equals
    const int eqTake = 6 - ngTot;

    float msum = 0.f;
    unsigned int locBits = 0u;
    int eqc = 0;
#pragma unroll
    for (int i = 0; i < 32; i++) {
      float v = bl[i];
      bool loc = (da[i] <= RADIUS) || (kb0 + i == nidx);
      bool sel;
      if (v > thr) sel = true;
      else if (v == thr) { sel = (eqStart + eqc) < eqTake; eqc++; }
      else sel = false;
      float sb = sel ? __expf(v - m6) * inv_e : 0.f;
      float bw = se[i] * inv_s;
      float lk = __expf(da[i] * da[i] * (-1.0f / (2.0f * RADIUS * RADIUS)));
      float mixed = fmaf(BSCALE, sb, loc ? bw * lk : 0.f);
      bl[i] = mixed;
      msum += mixed;
      if (loc) locBits |= (1u << i);
    }
    msum += __shfl_xor(msum, 32, 64);
    const float rinv = 1.0f / fmaxf(msum, 1e-6f);

    float lmass = 0.f, bmass = 0.f, md = 0.f;
#pragma unroll
    for (int i = 0; i < 32; i++) {
      float w = bl[i] * rinv;
      if ((locBits >> i) & 1u) lmass += w; else bmass += w;
      md = fmaf(w, da[i], md);
      smem[lsAddr(kb0 + i, row)] = w;       // park weights for P4 / coalesced store
    }
    lmass += __shfl_xor(lmass, 32, 64);
    bmass += __shfl_xor(bmass, 32, 64);
    md    += __shfl_xor(md, 32, 64);

    if (valid && h == 0) {
      out[oA + (size_t)rowg * 3 + 0] = ax;
      out[oA + (size_t)rowg * 3 + 1] = ay;
      out[oA + (size_t)rowg * 3 + 2] = az;
      out[oLM + rowg] = lmass;
      out[oBM + rowg] = bmass;
      out[oMD + rowg] = md;
      out[oR  + rowg] = RADIUS;
      out[oS  + rowg] = BSCALE;
    }
#undef CSEL
  }
  __syncthreads();

  // coalesced weights store: 8 float4 per thread
#pragma unroll
  for (int q = 0; q < 8; q++) {
    int slot = t + (q << 8);
    int r = slot >> 4;
    int c4 = (slot & 15) << 2;
    int rg = row0 + r;
    if (rg < B) {
      float4 w4;
      w4.x = smem[lsAddr(c4 + 0, r)];
      w4.y = smem[lsAddr(c4 + 1, r)];
      w4.z = smem[lsAddr(c4 + 2, r)];
      w4.w = smem[lsAddr(c4 + 3, r)];
      *(float4*)(out + oW + (size_t)rg * 64 + c4) = w4;
    }
  }

  // ---- Phase 4: patch_state[128][192] = Ws[128][64] @ pv[64][192] ----
  const int c0b = tc * 12;
  float acc2[8][12];
#pragma unroll
  for (int i = 0; i < 8; i++)
#pragma unroll
    for (int j = 0; j < 12; j++) acc2[i][j] = 0.f;

#pragma unroll 4
  for (int k = 0; k < PATCHES; k++) {
    float4 p0 = *(const float4*)(pv + (size_t)k * H + c0b);
    float4 p1 = *(const float4*)(pv + (size_t)k * H + c0b + 4);
    float4 p2 = *(const float4*)(pv + (size_t)k * H + c0b + 8);
    float pvv[12] = {p0.x, p0.y, p0.z, p0.w, p1.x, p1.y, p1.z, p1.w,
                     p2.x, p2.y, p2.z, p2.w};
    float wk[8];
#pragma unroll
    for (int i = 0; i < 8; i++) wk[i] = smem[lsAddr(k, r0 + i)];
#pragma unroll
    for (int i = 0; i < 8; i++)
#pragma unroll
      for (int j = 0; j < 12; j++)
        acc2[i][j] = fmaf(wk[i], pvv[j], acc2[i][j]);
  }
#pragma unroll
  for (int i = 0; i < 8; i++) {
    int rg = row0 + r0 + i;
    if (rg < B) {
      float* o = out + (size_t)rg * H + c0b;
      *(float4*)(o + 0) = make_float4(acc2[i][0], acc2[i][1], acc2[i][2], acc2[i][3]);
      *(float4*)(o + 4) = make_float4(acc2[i][4], acc2[i][5], acc2[i][6], acc2[i][7]);
      *(float4*)(o + 8) = make_float4(acc2[i][8], acc2[i][9], acc2[i][10], acc2[i][11]);
    }
  }
}

extern "C" void kernel_launch(void* const* d_in, const int* in_sizes, int n_in,
                              void* d_out, int out_size, void* d_ws, size_t ws_size,
                              hipStream_t stream) {
  const float* tok  = (const float*)d_in[0];
  const float* prv  = (const float*)d_in[1];
  const float* Wsel = (const float*)d_in[2];
  const float* bsel = (const float*)d_in[3];
  const float* Wbr  = (const float*)d_in[4];
  const float* bbr  = (const float*)d_in[5];
  const float* pv   = (const float*)d_in[6];
  const float* pp   = (const float*)d_in[7];
  float* out = (float*)d_out;
  const int B = in_sizes[0] / H;
  const int grid = (B + MT - 1) / MT;
  hipLaunchKernelGGL(taps_fused_kernel, dim3(grid), dim3(256), 0, stream,
                     tok, prv, Wsel, bsel, Wbr, bbr, pv, pp, out, B);
}